// Round 5
// baseline (148.112 us; speedup 1.0000x reference)
//
#include <hip/hip_runtime.h>
#include <hip/hip_bf16.h>
#include <cstdint>
#include <cstddef>

#define NQH 16
#define NKH 4
#define HN 128
#define QBLK 64
#define KBLK 64
// SCALE * log2(e): softmax computed in exp2 domain
#define QSCALE 0.12751589542585458f
#define TILEB 16384  // KBLK*HN*2 bytes per K or V tile

typedef __bf16 bf16x8 __attribute__((ext_vector_type(8)));
typedef float f32x4 __attribute__((ext_vector_type(4)));

__device__ __forceinline__ void gload16(const void* g, void* l) {
  __builtin_amdgcn_global_load_lds(
      (const __attribute__((address_space(1))) void*)g,
      (__attribute__((address_space(3))) void*)l, 16, 0, 0);
}

// ---- pre-kernel A: K f32 [T][4][128] -> Kb bf16 [4][T][128] ----
__global__ __launch_bounds__(256) void cvt_k(const float* __restrict__ K,
                                             __bf16* __restrict__ Kb, int T) {
  const size_t idx8 = ((size_t)blockIdx.x * 256 + threadIdx.x) * 8;
  const int d = (int)(idx8 & 127);
  const int kvh = (int)((idx8 >> 7) & 3);
  const size_t t = idx8 >> 9;
  float4 a = *(const float4*)&K[idx8];
  float4 b = *(const float4*)&K[idx8 + 4];
  bf16x8 f;
  f[0] = (__bf16)a.x; f[1] = (__bf16)a.y; f[2] = (__bf16)a.z; f[3] = (__bf16)a.w;
  f[4] = (__bf16)b.x; f[5] = (__bf16)b.y; f[6] = (__bf16)b.z; f[7] = (__bf16)b.w;
  *(bf16x8*)&Kb[(size_t)kvh * T * HN + t * HN + d] = f;
}

// ---- pre-kernel B: V f32 [T][4][128] -> Vb bf16 [4][128][T] (transposed) ----
__global__ __launch_bounds__(128) void cvt_v(const float* __restrict__ V,
                                             __bf16* __restrict__ Vb, int T) {
  const int d = threadIdx.x;           // 0..127
  const int t0 = blockIdx.x * 8;
  const int kvh = blockIdx.y;
  bf16x8 f;
#pragma unroll
  for (int i = 0; i < 8; ++i)
    f[i] = (__bf16)V[(size_t)(t0 + i) * (NKH * HN) + kvh * HN + d];
  *(bf16x8*)&Vb[(size_t)kvh * HN * T + (size_t)d * T + t0] = f;
}

// ---- main attention kernel (2-phase pipelined, double-buffered K/V) ----
__global__ __launch_bounds__(256, 2) void attn_mfma3(
    const float* __restrict__ Q, const __bf16* __restrict__ Kb,
    const __bf16* __restrict__ Vb, const int* __restrict__ cu,
    float* __restrict__ O, int T, int nseg) {
  const int h = blockIdx.y;
  const int r0 = (gridDim.x - 1 - blockIdx.x) * QBLK;  // heavy blocks first
  const int kvh = h >> 2;
  const int tid = threadIdx.x;
  const int w = tid >> 6, lane = tid & 63;
  const int ln = lane & 15, hi = lane >> 4;

  __shared__ __bf16 K_lds[2][KBLK * HN];  // 2 x 16 KB, swizzled [key][dim]
  __shared__ __bf16 V_lds[2][HN * KBLK];  // 2 x 16 KB, swizzled [dim][key]
  __shared__ __bf16 P_lds[QBLK][80];      // 10 KB, wave-private rows

  const __bf16* KbH = Kb + (size_t)kvh * T * HN;
  const __bf16* VbH = Vb + (size_t)kvh * HN * T;

  // ---- Q fragments (A-layout), scaled by 1/sqrt(d)*log2(e) ----
  bf16x8 qf[4];
  {
    const float* qp = &Q[(size_t)(r0 + w * 16 + ln) * (NQH * HN) + h * HN];
#pragma unroll
    for (int kc = 0; kc < 4; ++kc) {
      float4 a = *(const float4*)(qp + kc * 32 + hi * 8);
      float4 b = *(const float4*)(qp + kc * 32 + hi * 8 + 4);
      bf16x8 f;
      f[0] = (__bf16)(a.x * QSCALE); f[1] = (__bf16)(a.y * QSCALE);
      f[2] = (__bf16)(a.z * QSCALE); f[3] = (__bf16)(a.w * QSCALE);
      f[4] = (__bf16)(b.x * QSCALE); f[5] = (__bf16)(b.y * QSCALE);
      f[6] = (__bf16)(b.z * QSCALE); f[7] = (__bf16)(b.w * QSCALE);
      qf[kc] = f;
    }
  }

  // ---- per-row segment starts ----
  const int rowmin = r0 + w * 16;
  int row_[4], sst[4];
#pragma unroll
  for (int i = 0; i < 4; ++i) { row_[i] = rowmin + hi * 4 + i; sst[i] = 0; }
  int st0 = 0, sstw = 0;
  for (int s = 1; s < nseg; ++s) {
    const int c = cu[s];
    if (c <= r0) st0 = c;
    if (c <= rowmin + 15) sstw = c;  // sst of the wave's largest row
#pragma unroll
    for (int i = 0; i < 4; ++i)
      if (c <= row_[i]) sst[i] = c;
  }
  const int kstart = st0 & ~(KBLK - 1);
  const int nkb = (r0 + QBLK - kstart) / KBLK;

  float m_[4], l_[4];
  f32x4 acc[8];
#pragma unroll
  for (int i = 0; i < 4; ++i) { m_[i] = -1e30f; l_[i] = 0.f; }
#pragma unroll
  for (int dt = 0; dt < 8; ++dt) acc[dt] = (f32x4){0.f, 0.f, 0.f, 0.f};

  // ---- staging address components (loop-invariant) ----
  const int krow = w * 4 + hi;
  const int kcol = ((ln ^ (krow & 7)) << 3);
  const int vrow = w * 8 + (lane >> 3);
  const int vcol = (((lane & 7) ^ ((lane >> 3) & 7)) << 3);
  char* ldsK0 = (char*)&K_lds[0][0] + w * 1024 + (size_t)lane * 16;
  char* ldsV0 = (char*)&V_lds[0][0] + w * 1024 + (size_t)lane * 16;

  // ---- prologue: stage tile 0 into buffer 0 ----
#pragma unroll
  for (int j = 0; j < 4; ++j)
    gload16(KbH + (size_t)(kstart + j * 16 + krow) * HN + kcol, ldsK0 + j * 4096);
#pragma unroll
  for (int j = 0; j < 4; ++j)
    gload16(VbH + (size_t)(vrow + j * 32) * T + kstart + vcol, ldsV0 + j * 4096);
  __syncthreads();

  for (int it = 0; it < nkb; ++it) {
    const int kb = kstart + it * KBLK;
    const int cur = it & 1;

    // ---- issue next tile's DMA into the other buffer (overlaps compute) ----
    if (it + 1 < nkb) {
      const int kn = kb + KBLK;
      char* dK = ldsK0 + (cur ^ 1) * TILEB;
      char* dV = ldsV0 + (cur ^ 1) * TILEB;
#pragma unroll
      for (int j = 0; j < 4; ++j)
        gload16(KbH + (size_t)(kn + j * 16 + krow) * HN + kcol, dK + j * 4096);
#pragma unroll
      for (int j = 0; j < 4; ++j)
        gload16(VbH + (size_t)(vrow + j * 32) * T + kn + vcol, dV + j * 4096);
    }

    const char* Kc = (const char*)&K_lds[0][0] + cur * TILEB;
    const char* Vc = (const char*)&V_lds[0][0] + cur * TILEB;

    // ---- QK^T: S[16 rows][64 keys] per wave ----
    f32x4 s[4];
#pragma unroll
    for (int c = 0; c < 4; ++c) s[c] = (f32x4){0.f, 0.f, 0.f, 0.f};
    __builtin_amdgcn_s_setprio(1);
#pragma unroll
    for (int kc = 0; kc < 4; ++kc) {
#pragma unroll
      for (int c = 0; c < 4; ++c) {
        const int row = c * 16 + ln;
        const bf16x8 bf =
            *(const bf16x8*)(Kc + row * 256 + (((kc * 4 + hi) ^ (row & 7)) << 4));
        s[c] = __builtin_amdgcn_mfma_f32_16x16x32_bf16(qf[kc], bf, s[c], 0, 0, 0);
      }
    }
    __builtin_amdgcn_s_setprio(0);

    // ---- online softmax (exp2 domain, defer-max THR=8) ----
    const bool full = (kb >= sstw) & (kb + KBLK <= rowmin + 1);  // wave-uniform
    float mloc[4];
    if (full) {
#pragma unroll
      for (int i = 0; i < 4; ++i) {
        float mm = fmaxf(fmaxf(s[0][i], s[1][i]), fmaxf(s[2][i], s[3][i]));
#pragma unroll
        for (int off = 1; off < 16; off <<= 1) mm = fmaxf(mm, __shfl_xor(mm, off));
        mloc[i] = mm;
      }
    } else {
#pragma unroll
      for (int i = 0; i < 4; ++i) {
        float mm = -1e30f;
#pragma unroll
        for (int c = 0; c < 4; ++c) {
          const int key = kb + c * 16 + ln;
          const bool valid = (key >= sst[i]) & (key <= row_[i]);
          mm = fmaxf(mm, valid ? s[c][i] : -1e30f);
        }
#pragma unroll
        for (int off = 1; off < 16; off <<= 1) mm = fmaxf(mm, __shfl_xor(mm, off));
        mloc[i] = mm;
      }
    }
    bool need = false;
#pragma unroll
    for (int i = 0; i < 4; ++i) need |= (mloc[i] > m_[i] + 8.0f);
    if (__any(need)) {
#pragma unroll
      for (int i = 0; i < 4; ++i) {
        const float mnew = fmaxf(m_[i], mloc[i]);
        const float corr = exp2f(m_[i] - mnew);
        m_[i] = mnew;
        l_[i] *= corr;
#pragma unroll
        for (int dt = 0; dt < 8; ++dt) acc[dt][i] *= corr;
      }
    }
    if (full) {
#pragma unroll
      for (int i = 0; i < 4; ++i) {
        float ps = 0.f;
#pragma unroll
        for (int c = 0; c < 4; ++c) {
          const float p = exp2f(s[c][i] - m_[i]);
          ps += p;
          P_lds[w * 16 + hi * 4 + i][c * 16 + ln] = (__bf16)p;
        }
#pragma unroll
        for (int off = 1; off < 16; off <<= 1) ps += __shfl_xor(ps, off);
        l_[i] += ps;
      }
    } else {
#pragma unroll
      for (int i = 0; i < 4; ++i) {
        float ps = 0.f;
#pragma unroll
        for (int c = 0; c < 4; ++c) {
          const int key = kb + c * 16 + ln;
          const bool valid = (key >= sst[i]) & (key <= row_[i]);
          const float p = valid ? exp2f(s[c][i] - m_[i]) : 0.f;
          ps += p;
          P_lds[w * 16 + hi * 4 + i][c * 16 + ln] = (__bf16)p;
        }
#pragma unroll
        for (int off = 1; off < 16; off <<= 1) ps += __shfl_xor(ps, off);
        l_[i] += ps;
      }
    }

    // ---- PV: O[16 rows][128 dims] += P * V^T (wave-private P: no barrier) ----
    __builtin_amdgcn_s_setprio(1);
#pragma unroll
    for (int ch = 0; ch < 2; ++ch) {
      const bf16x8 pa = *(const bf16x8*)&P_lds[w * 16 + ln][ch * 32 + hi * 8];
#pragma unroll
      for (int dt = 0; dt < 8; ++dt) {
        const int vr = dt * 16 + ln;
        const bf16x8 vb =
            *(const bf16x8*)(Vc + vr * 128 + (((ch * 4 + hi) ^ (vr & 7)) << 4));
        acc[dt] = __builtin_amdgcn_mfma_f32_16x16x32_bf16(pa, vb, acc[dt], 0, 0, 0);
      }
    }
    __builtin_amdgcn_s_setprio(0);

    // one barrier per iter: drains this wave's DMA (vmcnt) + syncs buffer reuse
    __syncthreads();
  }

  // ---- epilogue ----
#pragma unroll
  for (int i = 0; i < 4; ++i) {
    const float inv = 1.0f / l_[i];
    float* op = &O[(size_t)row_[i] * (NQH * HN) + h * HN];
#pragma unroll
    for (int dt = 0; dt < 8; ++dt) op[dt * 16 + ln] = acc[dt][i] * inv;
  }
}

extern "C" void kernel_launch(void* const* d_in, const int* in_sizes, int n_in,
                              void* d_out, int out_size, void* d_ws, size_t ws_size,
                              hipStream_t stream) {
  const float* Q = (const float*)d_in[0];
  const float* K = (const float*)d_in[1];
  const float* V = (const float*)d_in[2];
  const int* cu = (const int*)d_in[3];
  float* O = (float*)d_out;

  const int T = in_sizes[0] / (NQH * HN);  // 4096
  const int nseg = in_sizes[3] - 1;        // 4

  const size_t need = (size_t)2 * NKH * T * HN * sizeof(__bf16);  // 8 MB
  if (ws_size < need) return;

  __bf16* Kb = (__bf16*)d_ws;                          // 4 MB
  __bf16* Vb = (__bf16*)d_ws + (size_t)NKH * T * HN;   // 4 MB

  const int nelem = T * NKH * HN;
  cvt_k<<<nelem / 8 / 256, 256, 0, stream>>>(K, Kb, T);
  cvt_v<<<dim3(T / 8, NKH), 128, 0, stream>>>(V, Vb, T);

  dim3 grid(T / QBLK, NQH);
  attn_mfma3<<<grid, 256, 0, stream>>>(Q, Kb, Vb, cu, O, T, nseg);
}

// Round 6
// 115.202 us; speedup vs baseline: 1.2857x; 1.2857x over previous
//
#include <hip/hip_runtime.h>
#include <hip/hip_bf16.h>
#include <cstdint>
#include <cstddef>

#define NQH 16
#define NKH 4
#define HN 128
#define QBLK 64
#define KBLK 64
// SCALE * log2(e): softmax computed in exp2 domain
#define QSCALE 0.12751589542585458f
#define TILEB 16384  // KBLK*HN*2 bytes per K or V tile

typedef __bf16 bf16x8 __attribute__((ext_vector_type(8)));
typedef __bf16 bf16x4 __attribute__((ext_vector_type(4)));
typedef float f32x4 __attribute__((ext_vector_type(4)));

__device__ __forceinline__ void gload16(const void* g, void* l) {
  __builtin_amdgcn_global_load_lds(
      (const __attribute__((address_space(1))) void*)g,
      (__attribute__((address_space(3))) void*)l, 16, 0, 0);
}

// ---- pre-kernel A: K f32 [T][4][128] -> Kb bf16 [4][T][128] ----
__global__ __launch_bounds__(256) void cvt_k(const float* __restrict__ K,
                                             __bf16* __restrict__ Kb, int T) {
  const size_t idx8 = ((size_t)blockIdx.x * 256 + threadIdx.x) * 8;
  const int d = (int)(idx8 & 127);
  const int kvh = (int)((idx8 >> 7) & 3);
  const size_t t = idx8 >> 9;
  float4 a = *(const float4*)&K[idx8];
  float4 b = *(const float4*)&K[idx8 + 4];
  bf16x8 f;
  f[0] = (__bf16)a.x; f[1] = (__bf16)a.y; f[2] = (__bf16)a.z; f[3] = (__bf16)a.w;
  f[4] = (__bf16)b.x; f[5] = (__bf16)b.y; f[6] = (__bf16)b.z; f[7] = (__bf16)b.w;
  *(bf16x8*)&Kb[(size_t)kvh * T * HN + t * HN + d] = f;
}

// ---- pre-kernel B: V f32 [T][4][128] -> Vb bf16 [4][128][T] (transposed) ----
__global__ __launch_bounds__(128) void cvt_v(const float* __restrict__ V,
                                             __bf16* __restrict__ Vb, int T) {
  const int d = threadIdx.x;           // 0..127
  const int t0 = blockIdx.x * 8;
  const int kvh = blockIdx.y;
  bf16x8 f;
#pragma unroll
  for (int i = 0; i < 8; ++i)
    f[i] = (__bf16)V[(size_t)(t0 + i) * (NKH * HN) + kvh * HN + d];
  *(bf16x8*)&Vb[(size_t)kvh * HN * T + (size_t)d * T + t0] = f;
}

// ---- one KV-block iteration (swapped-operand MFMA, per-lane softmax row) ----
// Lane owns q-row = r0 + w*16 + ln. sT[c][i] = S[q][kb + c*16 + hi*4 + i].
template <bool MASKED>
__device__ __forceinline__ void attn_iter(
    const char* Kc, const char* Vc, const bf16x8 qf[4],
    __bf16 (*P)[80], int w, int ln, int hi, int lim,
    float& m_, float& l_, f32x4* acc) {
  f32x4 sT[4];
#pragma unroll
  for (int c = 0; c < 4; ++c) sT[c] = (f32x4){0.f, 0.f, 0.f, 0.f};
  __builtin_amdgcn_s_setprio(1);
#pragma unroll
  for (int kc = 0; kc < 4; ++kc) {
#pragma unroll
    for (int c = 0; c < 4; ++c) {
      const int row = c * 16 + ln;
      const bf16x8 kf =
          *(const bf16x8*)(Kc + row * 256 + (((kc * 4 + hi) ^ (row & 7)) << 4));
      // swapped: A=K-frag, B=Q-frag -> D = S^T (lane col = q)
      sT[c] = __builtin_amdgcn_mfma_f32_16x16x32_bf16(kf, qf[kc], sT[c], 0, 0, 0);
    }
  }
  __builtin_amdgcn_s_setprio(0);

  if (MASKED) {
#pragma unroll
    for (int c = 0; c < 4; ++c)
#pragma unroll
      for (int i = 0; i < 4; ++i)
        sT[c][i] = (c * 16 + hi * 4 + i <= lim) ? sT[c][i] : -1e30f;
  }

  // ---- row max: 15 in-register fmax + 2 shfl ----
  float mm = fmaxf(
      fmaxf(fmaxf(fmaxf(sT[0][0], sT[0][1]), fmaxf(sT[0][2], sT[0][3])),
            fmaxf(fmaxf(sT[1][0], sT[1][1]), fmaxf(sT[1][2], sT[1][3]))),
      fmaxf(fmaxf(fmaxf(sT[2][0], sT[2][1]), fmaxf(sT[2][2], sT[2][3])),
            fmaxf(fmaxf(sT[3][0], sT[3][1]), fmaxf(sT[3][2], sT[3][3]))));
  mm = fmaxf(mm, __shfl_xor(mm, 16));
  mm = fmaxf(mm, __shfl_xor(mm, 32));

  // ---- defer-max rescale (THR=8) ----
  if (__any(mm > m_ + 8.0f)) {
    const float mnew = fmaxf(m_, mm);
    const float corr = exp2f(m_ - mnew);
    m_ = mnew;
    l_ *= corr;
#pragma unroll
    for (int dt = 0; dt < 8; ++dt) acc[dt] *= corr;
  }

  // ---- P = exp2(S - m), row sum, bf16 pack to LDS (4 x b64) ----
  float ps = 0.f;
#pragma unroll
  for (int c = 0; c < 4; ++c) {
    const float p0 = exp2f(sT[c][0] - m_);
    const float p1 = exp2f(sT[c][1] - m_);
    const float p2 = exp2f(sT[c][2] - m_);
    const float p3 = exp2f(sT[c][3] - m_);
    ps += (p0 + p1) + (p2 + p3);
    bf16x4 pk;
    pk[0] = (__bf16)p0; pk[1] = (__bf16)p1;
    pk[2] = (__bf16)p2; pk[3] = (__bf16)p3;
    *(bf16x4*)&P[w * 16 + ln][c * 16 + hi * 4] = pk;
  }
  ps += __shfl_xor(ps, 16);
  ps += __shfl_xor(ps, 32);
  l_ += ps;

  // ---- PV (swapped: A=V^T-frag, B=P^T-frag -> D = O^T, lane col = q) ----
  __builtin_amdgcn_s_setprio(1);
#pragma unroll
  for (int ch = 0; ch < 2; ++ch) {
    const bf16x8 pa = *(const bf16x8*)&P[w * 16 + ln][ch * 32 + hi * 8];
#pragma unroll
    for (int dt = 0; dt < 8; ++dt) {
      const int vr = dt * 16 + ln;
      const bf16x8 vb =
          *(const bf16x8*)(Vc + vr * 128 + (((ch * 4 + hi) ^ (vr & 7)) << 4));
      acc[dt] = __builtin_amdgcn_mfma_f32_16x16x32_bf16(vb, pa, acc[dt], 0, 0, 0);
    }
  }
  __builtin_amdgcn_s_setprio(0);
}

// ---- main attention kernel ----
__global__ __launch_bounds__(256, 2) void attn_mfma4(
    const float* __restrict__ Q, const __bf16* __restrict__ Kb,
    const __bf16* __restrict__ Vb, const int* __restrict__ cu,
    float* __restrict__ O, int T, int nseg) {
  const int h = blockIdx.y;
  const int r0 = (gridDim.x - 1 - blockIdx.x) * QBLK;  // heavy blocks first
  const int kvh = h >> 2;
  const int tid = threadIdx.x;
  const int w = tid >> 6, lane = tid & 63;
  const int ln = lane & 15, hi = lane >> 4;

  __shared__ __bf16 K_lds[2][KBLK * HN];  // 2 x 16 KB, swizzled [key][dim]
  __shared__ __bf16 V_lds[2][HN * KBLK];  // 2 x 16 KB, swizzled [dim][key]
  __shared__ __bf16 P_lds[QBLK][80];      // 10 KB, wave-private rows

  const __bf16* KbH = Kb + (size_t)kvh * T * HN;
  const __bf16* VbH = Vb + (size_t)kvh * HN * T;

  // ---- Q fragments (same mapping serves as B-operand), scaled ----
  bf16x8 qf[4];
  {
    const float* qp = &Q[(size_t)(r0 + w * 16 + ln) * (NQH * HN) + h * HN];
#pragma unroll
    for (int kc = 0; kc < 4; ++kc) {
      float4 a = *(const float4*)(qp + kc * 32 + hi * 8);
      float4 b = *(const float4*)(qp + kc * 32 + hi * 8 + 4);
      bf16x8 f;
      f[0] = (__bf16)(a.x * QSCALE); f[1] = (__bf16)(a.y * QSCALE);
      f[2] = (__bf16)(a.z * QSCALE); f[3] = (__bf16)(a.w * QSCALE);
      f[4] = (__bf16)(b.x * QSCALE); f[5] = (__bf16)(b.y * QSCALE);
      f[6] = (__bf16)(b.z * QSCALE); f[7] = (__bf16)(b.w * QSCALE);
      qf[kc] = f;
    }
  }

  // ---- segment start: uniform for the whole block (cu 64-aligned, QBLK=64) ----
  int st0 = 0;
  for (int s = 1; s < nseg; ++s) {
    const int c = cu[s];
    if (c <= r0) st0 = c;
  }
  const int kstart = st0 & ~(KBLK - 1);
  const int nkb = (r0 + QBLK - kstart) / KBLK;

  float m_ = -1e30f, l_ = 0.f;
  f32x4 acc[8];
#pragma unroll
  for (int dt = 0; dt < 8; ++dt) acc[dt] = (f32x4){0.f, 0.f, 0.f, 0.f};

  // ---- staging address components (loop-invariant) ----
  const int krow = w * 4 + hi;
  const int kcol = ((ln ^ (krow & 7)) << 3);
  const int vrow = w * 8 + (lane >> 3);
  const int vcol = (((lane & 7) ^ ((lane >> 3) & 7)) << 3);
  char* ldsK0 = (char*)&K_lds[0][0] + w * 1024 + (size_t)lane * 16;
  char* ldsV0 = (char*)&V_lds[0][0] + w * 1024 + (size_t)lane * 16;

  // ---- prologue: stage tile 0 into buffer 0 ----
#pragma unroll
  for (int j = 0; j < 4; ++j)
    gload16(KbH + (size_t)(kstart + j * 16 + krow) * HN + kcol, ldsK0 + j * 4096);
#pragma unroll
  for (int j = 0; j < 4; ++j)
    gload16(VbH + (size_t)(vrow + j * 32) * T + kstart + vcol, ldsV0 + j * 4096);
  __syncthreads();

  // ---- main loop: all-full iterations (no masking) ----
  for (int it = 0; it < nkb - 1; ++it) {
    const int cur = it & 1;
    // prefetch next tile into the other buffer (overlaps this iter's compute)
    const int kn = kstart + (it + 1) * KBLK;
    char* dK = ldsK0 + (cur ^ 1) * TILEB;
    char* dV = ldsV0 + (cur ^ 1) * TILEB;
#pragma unroll
    for (int j = 0; j < 4; ++j)
      gload16(KbH + (size_t)(kn + j * 16 + krow) * HN + kcol, dK + j * 4096);
#pragma unroll
    for (int j = 0; j < 4; ++j)
      gload16(VbH + (size_t)(vrow + j * 32) * T + kn + vcol, dV + j * 4096);

    attn_iter<false>((const char*)&K_lds[0][0] + cur * TILEB,
                     (const char*)&V_lds[0][0] + cur * TILEB, qf, P_lds, w, ln,
                     hi, 0, m_, l_, acc);
    __syncthreads();  // drains DMA (vmcnt) + buffer-reuse sync
  }

  // ---- final (diagonal) iteration, kb = r0: mask koff <= w*16+ln ----
  {
    const int cur = (nkb - 1) & 1;
    attn_iter<true>((const char*)&K_lds[0][0] + cur * TILEB,
                    (const char*)&V_lds[0][0] + cur * TILEB, qf, P_lds, w, ln,
                    hi, w * 16 + ln, m_, l_, acc);
  }

  // ---- epilogue: lane owns row rowq; acc[dt][i] = O[rowq][dt*16+hi*4+i] ----
  const int rowq = r0 + w * 16 + ln;
  const float inv = 1.0f / l_;
  float* op = &O[(size_t)rowq * (NQH * HN) + h * HN];
#pragma unroll
  for (int dt = 0; dt < 8; ++dt) {
    f32x4 res = acc[dt] * inv;
    *(f32x4*)&op[dt * 16 + hi * 4] = res;
  }
}

extern "C" void kernel_launch(void* const* d_in, const int* in_sizes, int n_in,
                              void* d_out, int out_size, void* d_ws, size_t ws_size,
                              hipStream_t stream) {
  const float* Q = (const float*)d_in[0];
  const float* K = (const float*)d_in[1];
  const float* V = (const float*)d_in[2];
  const int* cu = (const int*)d_in[3];
  float* O = (float*)d_out;

  const int T = in_sizes[0] / (NQH * HN);  // 4096
  const int nseg = in_sizes[3] - 1;        // 4

  const size_t need = (size_t)2 * NKH * T * HN * sizeof(__bf16);  // 8 MB
  if (ws_size < need) return;

  __bf16* Kb = (__bf16*)d_ws;                          // 4 MB
  __bf16* Vb = (__bf16*)d_ws + (size_t)NKH * T * HN;   // 4 MB

  const int nelem = T * NKH * HN;
  cvt_k<<<nelem / 8 / 256, 256, 0, stream>>>(K, Kb, T);
  cvt_v<<<dim3(T / 8, NKH), 128, 0, stream>>>(V, Vb, T);

  dim3 grid(T / QBLK, NQH);
  attn_mfma4<<<grid, 256, 0, stream>>>(Q, Kb, Vb, cu, O, T, nseg);
}

// Round 7
// 89.328 us; speedup vs baseline: 1.6581x; 1.2897x over previous
//
#include <hip/hip_runtime.h>
#include <hip/hip_bf16.h>
#include <cstdint>
#include <cstddef>

#define NQH 16
#define NKH 4
#define HN 128
#define QBLK 64
#define KBLK 64
// SCALE * log2(e): softmax computed in exp2 domain
#define QSCALE 0.12751589542585458f
#define TILEB 16384  // KBLK*HN*2 bytes per K or V tile

typedef __bf16 bf16x8 __attribute__((ext_vector_type(8)));
typedef float f32x4 __attribute__((ext_vector_type(4)));

__device__ __forceinline__ void gload16(const void* g, void* l) {
  __builtin_amdgcn_global_load_lds(
      (const __attribute__((address_space(1))) void*)g,
      (__attribute__((address_space(3))) void*)l, 16, 0, 0);
}

// ---- pre-kernel A: K f32 [T][4][128] -> Kb bf16 [4][T][128] ----
__global__ __launch_bounds__(256) void cvt_k(const float* __restrict__ K,
                                             __bf16* __restrict__ Kb, int T) {
  const size_t idx8 = ((size_t)blockIdx.x * 256 + threadIdx.x) * 8;
  const int d = (int)(idx8 & 127);
  const int kvh = (int)((idx8 >> 7) & 3);
  const size_t t = idx8 >> 9;
  float4 a = *(const float4*)&K[idx8];
  float4 b = *(const float4*)&K[idx8 + 4];
  bf16x8 f;
  f[0] = (__bf16)a.x; f[1] = (__bf16)a.y; f[2] = (__bf16)a.z; f[3] = (__bf16)a.w;
  f[4] = (__bf16)b.x; f[5] = (__bf16)b.y; f[6] = (__bf16)b.z; f[7] = (__bf16)b.w;
  *(bf16x8*)&Kb[(size_t)kvh * T * HN + t * HN + d] = f;
}

// ---- pre-kernel B: V f32 [T][4][128] -> Vb bf16 [4][128][T] (transposed) ----
__global__ __launch_bounds__(128) void cvt_v(const float* __restrict__ V,
                                             __bf16* __restrict__ Vb, int T) {
  const int d = threadIdx.x;           // 0..127
  const int t0 = blockIdx.x * 8;
  const int kvh = blockIdx.y;
  bf16x8 f;
#pragma unroll
  for (int i = 0; i < 8; ++i)
    f[i] = (__bf16)V[(size_t)(t0 + i) * (NKH * HN) + kvh * HN + d];
  *(bf16x8*)&Vb[(size_t)kvh * HN * T + (size_t)d * T + t0] = f;
}

// ---- one KV-block iteration: swapped MFMA, in-register P (permuted K rows) ----
// Lane owns q-row = r0 + wl*16 + ln.
// sT[c][i] = S[q][kb + koff], koff = (c>>1)*32 + hi*8 + (c&1)*4 + i.
template <bool MASKED>
__device__ __forceinline__ void attn_iter(const char* Kc, const char* Vc,
                                          const bf16x8 qf[4], int ln, int hi,
                                          int lim, float& m_, float& l_,
                                          f32x4* acc) {
  f32x4 sT[4];
#pragma unroll
  for (int c = 0; c < 4; ++c) sT[c] = (f32x4){0.f, 0.f, 0.f, 0.f};
  __builtin_amdgcn_s_setprio(1);
#pragma unroll
  for (int kc = 0; kc < 4; ++kc) {
#pragma unroll
    for (int c = 0; c < 4; ++c) {
      const int row = c * 16 + ln;
      const bf16x8 kf =
          *(const bf16x8*)(Kc + row * 256 + (((kc * 4 + hi) ^ (row & 7)) << 4));
      sT[c] = __builtin_amdgcn_mfma_f32_16x16x32_bf16(kf, qf[kc], sT[c], 0, 0, 0);
    }
  }
  __builtin_amdgcn_s_setprio(0);

  if (MASKED) {
#pragma unroll
    for (int c = 0; c < 4; ++c)
#pragma unroll
      for (int i = 0; i < 4; ++i) {
        const int koff = ((c >> 1) << 5) + hi * 8 + ((c & 1) << 2) + i;
        sT[c][i] = (koff <= lim) ? sT[c][i] : -1e30f;
      }
  }

  // ---- row max: 15 in-register fmax + 2 shfl ----
  float mm = fmaxf(
      fmaxf(fmaxf(fmaxf(sT[0][0], sT[0][1]), fmaxf(sT[0][2], sT[0][3])),
            fmaxf(fmaxf(sT[1][0], sT[1][1]), fmaxf(sT[1][2], sT[1][3]))),
      fmaxf(fmaxf(fmaxf(sT[2][0], sT[2][1]), fmaxf(sT[2][2], sT[2][3])),
            fmaxf(fmaxf(sT[3][0], sT[3][1]), fmaxf(sT[3][2], sT[3][3]))));
  mm = fmaxf(mm, __shfl_xor(mm, 16));
  mm = fmaxf(mm, __shfl_xor(mm, 32));

  // ---- defer-max rescale (THR=8) ----
  if (__any(mm > m_ + 8.0f)) {
    const float mnew = fmaxf(m_, mm);
    const float corr = exp2f(m_ - mnew);
    m_ = mnew;
    l_ *= corr;
#pragma unroll
    for (int dt = 0; dt < 8; ++dt) acc[dt] *= corr;
  }

  // ---- P = exp2(S - m), row sum; pack directly into PV B-fragments ----
  float p[4][4];
  float ps = 0.f;
#pragma unroll
  for (int c = 0; c < 4; ++c) {
#pragma unroll
    for (int i = 0; i < 4; ++i) {
      p[c][i] = exp2f(sT[c][i] - m_);
      ps += p[c][i];
    }
  }
  ps += __shfl_xor(ps, 16);
  ps += __shfl_xor(ps, 32);
  l_ += ps;

  bf16x8 pa[2];
#pragma unroll
  for (int ch = 0; ch < 2; ++ch)
#pragma unroll
    for (int e = 0; e < 8; ++e)
      pa[ch][e] = (__bf16)p[2 * ch + (e >> 2)][e & 3];

  // ---- PV (swapped: A=V^T-frag, B=P-frag -> D = O^T, lane col = q) ----
  __builtin_amdgcn_s_setprio(1);
#pragma unroll
  for (int ch = 0; ch < 2; ++ch) {
#pragma unroll
    for (int dt = 0; dt < 8; ++dt) {
      const int vr = dt * 16 + ln;
      const bf16x8 vb =
          *(const bf16x8*)(Vc + vr * 128 + (((ch * 4 + hi) ^ (vr & 7)) << 4));
      acc[dt] = __builtin_amdgcn_mfma_f32_16x16x32_bf16(vb, pa[ch], acc[dt], 0, 0, 0);
    }
  }
  __builtin_amdgcn_s_setprio(0);
}

// ---- main kernel: 8 waves, 2 q-heads share KV tiles (GQA) ----
__global__ __launch_bounds__(512, 4) void attn_mfma5(
    const float* __restrict__ Q, const __bf16* __restrict__ Kb,
    const __bf16* __restrict__ Vb, const int* __restrict__ cu,
    float* __restrict__ O, int T, int nseg) {
  const int tid = threadIdx.x;
  const int w = tid >> 6, lane = tid & 63;
  const int wg = w >> 2, wl = w & 3;   // head-group, wave-within-head
  const int ln = lane & 15, hi = lane >> 4;
  const int y = blockIdx.y;            // 0..7: (kvh, head-pair)
  const int kvh = y >> 1;
  const int h = kvh * 4 + (y & 1) * 2 + wg;
  const int r0 = (gridDim.x - 1 - blockIdx.x) * QBLK;  // heavy blocks first

  __shared__ __bf16 K_lds[2][KBLK * HN];  // 2 x 16 KB, permuted+swizzled rows
  __shared__ __bf16 V_lds[2][HN * KBLK];  // 2 x 16 KB, swizzled [dim][key]

  const __bf16* KbH = Kb + (size_t)kvh * T * HN;
  const __bf16* VbH = Vb + (size_t)kvh * HN * T;

  // ---- Q fragments (B-operand mapping), scaled ----
  bf16x8 qf[4];
  {
    const float* qp = &Q[(size_t)(r0 + wl * 16 + ln) * (NQH * HN) + h * HN];
#pragma unroll
    for (int kc = 0; kc < 4; ++kc) {
      float4 a = *(const float4*)(qp + kc * 32 + hi * 8);
      float4 b = *(const float4*)(qp + kc * 32 + hi * 8 + 4);
      bf16x8 f;
      f[0] = (__bf16)(a.x * QSCALE); f[1] = (__bf16)(a.y * QSCALE);
      f[2] = (__bf16)(a.z * QSCALE); f[3] = (__bf16)(a.w * QSCALE);
      f[4] = (__bf16)(b.x * QSCALE); f[5] = (__bf16)(b.y * QSCALE);
      f[6] = (__bf16)(b.z * QSCALE); f[7] = (__bf16)(b.w * QSCALE);
      qf[kc] = f;
    }
  }

  // ---- segment start (cu values are 64-aligned; uniform per tile) ----
  int st0 = 0;
  for (int s = 1; s < nseg; ++s) {
    const int c = cu[s];
    if (c <= r0) st0 = c;
  }
  const int kstart = st0 & ~(KBLK - 1);
  const int nkb = (r0 + QBLK - kstart) / KBLK;

  float m_ = -1e30f, l_ = 0.f;
  f32x4 acc[8];
#pragma unroll
  for (int dt = 0; dt < 8; ++dt) acc[dt] = (f32x4){0.f, 0.f, 0.f, 0.f};

  // ---- staging invariants ----
  // K: LDS row R = j*32 + kR (j=0,1), slot ln. Row R holds key kb + sigma(R):
  //   c=R>>4, r=R&15, sigma = (c>>1)*32 + (r>>2)*8 + (c&1)*4 + (r&3)
  const int kR = w * 4 + hi;
  int keyoff[2];
#pragma unroll
  for (int j = 0; j < 2; ++j) {
    const int R = j * 32 + kR;
    const int c = R >> 4, r = R & 15;
    keyoff[j] = ((c >> 1) << 5) + ((r >> 2) << 3) + ((c & 1) << 2) + (r & 3);
  }
  const int kcol = ((ln ^ (kR & 7)) << 3);
  // V: LDS row d = j*64 + vrow, slot lane&7
  const int vrow = w * 8 + (lane >> 3);
  const int vcol = (((lane & 7) ^ ((lane >> 3) & 7)) << 3);
  char* ldsK0 = (char*)&K_lds[0][0] + w * 1024 + (size_t)lane * 16;
  char* ldsV0 = (char*)&V_lds[0][0] + w * 1024 + (size_t)lane * 16;

  // ---- prologue: stage tile 0 into buffer 0 ----
#pragma unroll
  for (int j = 0; j < 2; ++j)
    gload16(KbH + (size_t)(kstart + keyoff[j]) * HN + kcol, ldsK0 + j * 8192);
#pragma unroll
  for (int j = 0; j < 2; ++j)
    gload16(VbH + (size_t)(j * 64 + vrow) * T + kstart + vcol, ldsV0 + j * 8192);
  __syncthreads();

  // ---- main loop: full (unmasked) iterations with prefetch ----
  for (int it = 0; it < nkb - 1; ++it) {
    const int cur = it & 1;
    const int kn = kstart + (it + 1) * KBLK;
    char* dK = ldsK0 + (cur ^ 1) * TILEB;
    char* dV = ldsV0 + (cur ^ 1) * TILEB;
#pragma unroll
    for (int j = 0; j < 2; ++j)
      gload16(KbH + (size_t)(kn + keyoff[j]) * HN + kcol, dK + j * 8192);
#pragma unroll
    for (int j = 0; j < 2; ++j)
      gload16(VbH + (size_t)(j * 64 + vrow) * T + kn + vcol, dV + j * 8192);

    attn_iter<false>((const char*)&K_lds[0][0] + cur * TILEB,
                     (const char*)&V_lds[0][0] + cur * TILEB, qf, ln, hi, 0, m_,
                     l_, acc);
    __syncthreads();  // drains DMA (vmcnt) + buffer-reuse sync
  }

  // ---- final (diagonal) iteration: mask koff <= wl*16+ln ----
  {
    const int cur = (nkb - 1) & 1;
    attn_iter<true>((const char*)&K_lds[0][0] + cur * TILEB,
                    (const char*)&V_lds[0][0] + cur * TILEB, qf, ln, hi,
                    wl * 16 + ln, m_, l_, acc);
  }

  // ---- epilogue: acc[dt][i] = O[rowq][dt*16 + hi*4 + i] ----
  const int rowq = r0 + wl * 16 + ln;
  const float inv = 1.0f / l_;
  float* op = &O[(size_t)rowq * (NQH * HN) + h * HN];
#pragma unroll
  for (int dt = 0; dt < 8; ++dt) {
    f32x4 res = acc[dt] * inv;
    *(f32x4*)&op[dt * 16 + hi * 4] = res;
  }
}

extern "C" void kernel_launch(void* const* d_in, const int* in_sizes, int n_in,
                              void* d_out, int out_size, void* d_ws, size_t ws_size,
                              hipStream_t stream) {
  const float* Q = (const float*)d_in[0];
  const float* K = (const float*)d_in[1];
  const float* V = (const float*)d_in[2];
  const int* cu = (const int*)d_in[3];
  float* O = (float*)d_out;

  const int T = in_sizes[0] / (NQH * HN);  // 4096
  const int nseg = in_sizes[3] - 1;        // 4

  const size_t need = (size_t)2 * NKH * T * HN * sizeof(__bf16);  // 8 MB
  if (ws_size < need) return;

  __bf16* Kb = (__bf16*)d_ws;                          // 4 MB
  __bf16* Vb = (__bf16*)d_ws + (size_t)NKH * T * HN;   // 4 MB

  const int nelem = T * NKH * HN;
  cvt_k<<<nelem / 8 / 256, 256, 0, stream>>>(K, Kb, T);
  cvt_v<<<dim3(T / 8, NKH), 128, 0, stream>>>(V, Vb, T);

  dim3 grid(T / QBLK, NKH * 2);  // 2 q-heads per block share KV
  attn_mfma5<<<grid, 512, 0, stream>>>(Q, Kb, Vb, cu, O, T, nseg);
}